// Round 18
// baseline (59.445 us; speedup 1.0000x reference)
//
#include <hip/hip_runtime.h>

#define BATCH 4
#define NPTS 4096
#define DF 64
#define ITILE 256              // 8 waves x 32 rows
#define JSPLIT 8
#define JCH (NPTS/JSPLIT)      // 512
#define JT 32
#define NT (JCH/JT)            // 16 (even)
#define AUGD 96                // 80 feature (5x K16) + 16 spatial (1x K16)
#define TPB 128                // j-tiles per batch (4096/32)
#define TILEU 3072             // ushorts per packed tile (6 slices x 512)
#define LOG2E 1.4426950408889634f

typedef short short8 __attribute__((ext_vector_type(8)));
typedef float f32x16 __attribute__((ext_vector_type(16)));

__device__ __forceinline__ unsigned short bfb(float x){
  unsigned int u = __float_as_uint(x);
  u += 0x7FFFu + ((u>>16)&1u);          // RNE
  return (unsigned short)(u>>16);
}
__device__ __forceinline__ float bff(unsigned short h){
  return __uint_as_float(((unsigned int)h)<<16);
}
__device__ __forceinline__ float fexp2(float x){   // raw v_exp_f32 (2^x)
  float r; asm("v_exp_f32 %0, %1" : "=v"(r) : "v"(x)); return r;
}

// Packed-tile address (in ushorts) for element col c of j-row jj, batch b.
// Layout [b][T][s][h*32+r][e] (validated absmax 0.0 R15-R17).
__device__ __forceinline__ size_t jaddr(int b, int jj, int c){
  int T = jj>>5, r = jj&31;
  int s = c>>4, h = (c>>3)&1, e = c&7;
  return ((size_t)(b*TPB + T))*TILEU + s*512 + (h*32 + r)*8 + e;
}

// ---------------------------------------------------------------- prepass ---
// Same math/arithmetic order as R15-R17 (validated absmax 0.0), but the aux
// columns (64..95) are computed by ALL 64 LANES IN PARALLEL: lanes 0..31
// each produce one J-aux column, lanes 32..63 one I-aux column — replacing
// the old ~45 serial scattered stores on lane 0 (the divergence sink).
__global__ void df_prep(const float* __restrict__ pts,
                        const float* __restrict__ f1,
                        const float* __restrict__ f2,
                        unsigned short* __restrict__ augI,
                        unsigned short* __restrict__ augJ)
{
  int wid = (blockIdx.x<<2) + (threadIdx.x>>6);
  int lane = threadIdx.x & 63;
  if (wid >= BATCH*NPTS) return;
  const int b = wid>>12, jj = wid&4095;
  float v1 = f1[(size_t)wid*DF + lane];
  float v2 = f2[(size_t)wid*DF + lane];
  float r2 = v2*v2;
  #pragma unroll
  for (int s=32;s>=1;s>>=1)
    r2 += __shfl_xor(r2, s);
  augI[(size_t)wid*AUGD + lane] = bfb(2.0f*LOG2E*v1);
  augJ[jaddr(b, jj, lane)] = bfb(v2);

  // broadcast scalars (same-address loads; every lane computes them)
  float px = pts[(size_t)wid*3+0]/0.05f;
  float py = pts[(size_t)wid*3+1]/0.05f;
  float pz = pts[(size_t)wid*3+2]/0.05f;
  float nss = px*px+py*py+pz*pz;

  // feature-norm 3-way split (identical op order to validated prep)
  float fn = LOG2E*r2;
  unsigned short f0_ = bfb(fn); float fr = fn - bff(f0_);
  unsigned short f1_ = bfb(fr); fr -= bff(f1_);
  unsigned short f2_ = bfb(fr);
  // spatial-norm 3-way split
  float sn = LOG2E*nss;
  unsigned short s0_ = bfb(sn); float sr = sn - bff(s0_);
  unsigned short s1_ = bfb(sr); sr -= bff(s1_);
  unsigned short s2_ = bfb(sr);
  // J-side coordinate hi/lo split
  unsigned short hx=bfb(px), hy=bfb(py), hz=bfb(pz);
  unsigned short lxb=bfb(px-bff(hx)), lyb=bfb(py-bff(hy)), lzb=bfb(pz-bff(hz));
  // I-side (2*log2e*coord) hi/lo split
  float sx=2.f*LOG2E*px, sy=2.f*LOG2E*py, sz=2.f*LOG2E*pz;
  unsigned short h2x=bfb(sx), h2y=bfb(sy), h2z=bfb(sz);
  unsigned short l2x=bfb(sx-bff(h2x)), l2y=bfb(sy-bff(h2y)), l2z=bfb(sz-bff(h2z));
  unsigned short mone = bfb(-1.0f), one = bfb(1.0f);

  const int k = lane & 31;              // aux column 64+k
  const int idx = (k-16)%3, grp = (k-16)/3;
  unsigned short hj  = idx==0?hx :(idx==1?hy :hz );
  unsigned short lj  = idx==0?lxb:(idx==1?lyb:lzb);
  unsigned short hi2 = idx==0?h2x:(idx==1?h2y:h2z);
  unsigned short li2 = idx==0?l2x:(idx==1?l2y:l2z);

  unsigned short jv, iv;
  if (k<3)       { jv = (k==0)?f0_:(k==1)?f1_:f2_;  iv = mone; }
  else if (k<16) { jv = 0;                           iv = 0;    }
  else if (k<28) { jv = (grp&1)? lj : hj;            iv = (grp>=2)? li2 : hi2; }
  else if (k<31) { jv = (k==28)?s0_:(k==29)?s1_:s2_; iv = mone; }
  else           { jv = one;                         iv = bfb(-sn); }

  if (lane < 32) augJ[jaddr(b, jj, 64+k)] = jv;
  else           augI[(size_t)wid*AUGD + 64 + k] = iv;
}

// ------------------------------------------------------------------- main ---
// R16 VERBATIM (best measured: total 52.1us, absmax 0.0; FETCH 14MB, no
// spill). 512x512 grid x=jc; packed coalesced j-loads; named-reg double
// buffer; independent even/odd accumulator streams; defer-max.

#define LOAD6I(p, v0,v1,v2,v3,v4,v5)                 \
  v0 = *(const short8*)(p);                          \
  v1 = *(const short8*)((p)+16);                     \
  v2 = *(const short8*)((p)+32);                     \
  v3 = *(const short8*)((p)+48);                     \
  v4 = *(const short8*)((p)+64);                     \
  v5 = *(const short8*)((p)+80);

#define LOAD6J(p, v0,v1,v2,v3,v4,v5)                 \
  v0 = *(const short8*)(p);                          \
  v1 = *(const short8*)((p)+512);                    \
  v2 = *(const short8*)((p)+1024);                   \
  v3 = *(const short8*)((p)+1536);                   \
  v4 = *(const short8*)((p)+2048);                   \
  v5 = *(const short8*)((p)+2560);

#define MFMA_BF16 __builtin_amdgcn_mfma_f32_32x32x16_bf16

#define TILE_BODY(v0,v1,v2,v3,v4,v5, M,LP,SA,LQ,SB,SC, PRELOAD)          \
  {                                                                      \
    f32x16 z = {};                                                       \
    f32x16 f0 = MFMA_BF16(v0, bfr0, z, 0,0,0);                           \
    f0 = MFMA_BF16(v1, bfr1, f0,0,0,0);                                  \
    f0 = MFMA_BF16(v2, bfr2, f0,0,0,0);                                  \
    f32x16 f1 = MFMA_BF16(v3, bfr3, z,0,0,0);                            \
    f1 = MFMA_BF16(v4, bfr4, f1,0,0,0);                                  \
    f32x16 accS = MFMA_BF16(v5, bfr5, z,0,0,0);                          \
    PRELOAD                                                              \
    f32x16 accF = f0 + f1;                                               \
    float t0 = fmaxf(accF[0],accF[1]),  t1 = fmaxf(accF[2],accF[3]);     \
    float t2 = fmaxf(accF[4],accF[5]),  t3 = fmaxf(accF[6],accF[7]);     \
    float t4 = fmaxf(accF[8],accF[9]),  t5 = fmaxf(accF[10],accF[11]);   \
    float t6 = fmaxf(accF[12],accF[13]),t7 = fmaxf(accF[14],accF[15]);   \
    t0 = fmaxf(t0,t1); t2 = fmaxf(t2,t3);                                \
    t4 = fmaxf(t4,t5); t6 = fmaxf(t6,t7);                                \
    float tmax = fmaxf(fmaxf(t0,t2), fmaxf(t4,t6));                      \
    if (!__all(tmax <= M)){                                              \
      float mnew = fmaxf(M, tmax);                                       \
      float sg = fexp2(M - mnew);                                        \
      float sg2 = sg*sg;                                                 \
      LQ *= sg; SB *= sg2; SC *= sg; M = mnew;                           \
    }                                                                    \
    _Pragma("unroll")                                                    \
    for (int r=0;r<16;r++){                                              \
      float pv = fexp2(accS[r]);                                         \
      float qv = fexp2(accF[r]-M);                                       \
      LP += pv;                                                          \
      SA = fmaf(pv,pv,SA);                                               \
      LQ += qv;                                                          \
      SB = fmaf(qv,qv,SB);                                               \
      SC = fmaf(pv,qv,SC);                                               \
    }                                                                    \
  }

__global__ __launch_bounds__(512, 2)
void df_main(const unsigned short* __restrict__ augI,
             const unsigned short* __restrict__ augJ,
             float* __restrict__ part)
{
  const int tid = threadIdx.x;
  const int wave = tid>>6, lane = tid&63;
  const int il = lane&31, hk = lane>>5;
  const int jc = blockIdx.x, it = blockIdx.y, b = blockIdx.z;

  const int irow = it*ITILE + wave*32 + il;
  const size_t ibase = ((size_t)(b*NPTS + irow))*AUGD;
  short8 bfr0,bfr1,bfr2,bfr3,bfr4,bfr5;
  LOAD6I(augI + ibase + hk*8, bfr0,bfr1,bfr2,bfr3,bfr4,bfr5)

  const unsigned short* jp =
      augJ + ((size_t)(b*TPB + jc*NT))*TILEU + lane*8;
  const size_t step = TILEU;             // 3072 ushorts per tile

  float lP0=0.f, sA0=0.f, m0=-1e30f, lQ0=0.f, sB0=0.f, sC0=0.f;
  float lP1=0.f, sA1=0.f, m1=-1e30f, lQ1=0.f, sB1=0.f, sC1=0.f;

  short8 xa0,xa1,xa2,xa3,xa4,xa5;        // buffer A (even tiles)
  short8 xb0,xb1,xb2,xb3,xb4,xb5;        // buffer B (odd tiles)
  LOAD6J(jp,        xa0,xa1,xa2,xa3,xa4,xa5)   // t = 0
  LOAD6J(jp + step, xb0,xb1,xb2,xb3,xb4,xb5)   // t = 1
  const unsigned short* jpf = jp + 2*step;     // next to fetch: t = 2

  for (int t=0; t<NT; t+=2){
    TILE_BODY(xa0,xa1,xa2,xa3,xa4,xa5, m0,lP0,sA0,lQ0,sB0,sC0,
      if (t+2 < NT){
        LOAD6J(jpf, xa0,xa1,xa2,xa3,xa4,xa5)   // prefetch t+2 into dead A
        jpf += step;
      })
    TILE_BODY(xb0,xb1,xb2,xb3,xb4,xb5, m1,lP1,sA1,lQ1,sB1,sC1,
      if (t+3 < NT){
        LOAD6J(jpf, xb0,xb1,xb2,xb3,xb4,xb5)   // prefetch t+3 into dead B
        jpf += step;
      })
  }

  // merge stream 1 into stream 0 (disjoint j-subsets; exact rebase)
  float mS = fmaxf(m0, m1);
  float e0 = fexp2(m0-mS), e1 = fexp2(m1-mS);
  float lP = lP0 + lP1;
  float sA = sA0 + sA1;
  float lQ = lQ0*e0 + lQ1*e1;
  float sB = sB0*e0*e0 + sB1*e1*e1;
  float sC = sC0*e0 + sC1*e1;
  float m  = mS;

  // merge the two hk-halves (disjoint j-subsets of same i-row) in-register
  float mo  = __shfl_xor(m, 32);
  float lPo = __shfl_xor(lP,32);
  float sAo = __shfl_xor(sA,32);
  float lQo = __shfl_xor(lQ,32);
  float sBo = __shfl_xor(sB,32);
  float sCo = __shfl_xor(sC,32);
  float mm = fmaxf(m, mo);
  float s0 = fexp2(m-mm), s1 = fexp2(mo-mm);
  lP += lPo; sA += sAo;
  lQ = lQ*s0 + lQo*s1;
  sB = sB*s0*s0 + sBo*s1*s1;
  sC = sC*s0 + sCo*s1;

  if (hk==0){
    const size_t pidx = (((size_t)jc)*((size_t)BATCH*NPTS)
                         + (size_t)b*NPTS + irow)*8;
    float4 v0 = {lP, sA, mm, lQ};
    float4 v1 = {sB, sC, 0.f, 0.f};
    *(float4*)(part + pidx)     = v0;    // full 32B/row -> no partial lines
    *(float4*)(part + pidx + 4) = v1;
  }
}

// ------------------------------------------------- fused reduce + final ----
// One block per batch (1024 thr). Each thread folds 4 i-rows across the 8
// partial sets, then wave-shfl + LDS tree reduce -> out[b]. Replaces the
// old df_reduce + df_final pair (one less launch, no ws2 round-trip).
__global__ __launch_bounds__(1024)
void df_reduce2(const float* __restrict__ part,
                const float* __restrict__ w,
                float* __restrict__ out)
{
  const int b = blockIdx.x, tid = threadIdx.x;
  const size_t stride = (size_t)BATCH*NPTS*8;
  float acc = 0.f;
  for (int i = tid; i < NPTS; i += 1024){
    const size_t base = ((size_t)b*NPTS + i)*8;
    float mx = -1e30f;
    #pragma unroll
    for (int k=0;k<JSPLIT;k++)
      mx = fmaxf(mx, part[base + (size_t)k*stride + 2]);
    float lP=0,sA=0,lQ=0,sB=0,sC=0;
    #pragma unroll
    for (int k=0;k<JSPLIT;k++){
      const float* pp = part + base + (size_t)k*stride;
      lP += pp[0]; sA += pp[1];
      float sg = fexp2(pp[2]-mx);
      lQ += sg*pp[3]; sB += sg*sg*pp[4]; sC += sg*pp[5];
    }
    float res = sA/(lP*lP) + sB/(lQ*lQ) - 2.0f*sC/(lP*lQ);
    acc += w[(size_t)b*NPTS + i]*res;
  }
  #pragma unroll
  for (int s=32;s>=1;s>>=1) acc += __shfl_xor(acc, s);
  __shared__ float red[16];
  const int wv = tid>>6, ln = tid&63;
  if (ln==0) red[wv] = acc;
  __syncthreads();
  if (tid < 16){
    float v = red[tid];
    #pragma unroll
    for (int s=8;s>=1;s>>=1) v += __shfl_xor(v, s, 16);
    if (tid==0) out[b] = v;
  }
}

// ----------------------------------------------------------------- launch ---
extern "C" void kernel_launch(void* const* d_in, const int* in_sizes, int n_in,
                              void* d_out, int out_size, void* d_ws, size_t ws_size,
                              hipStream_t stream) {
  const float* pts = (const float*)d_in[0];
  const float* w   = (const float*)d_in[1];
  const float* f1  = (const float*)d_in[2];
  const float* f2  = (const float*)d_in[3];
  float* out = (float*)d_out;

  unsigned char* ws = (unsigned char*)d_ws;
  const size_t AUG_BYTES = (size_t)BATCH*NPTS*AUGD*2;        // 3,145,728 each
  unsigned short* augI = (unsigned short*)(ws);
  unsigned short* augJ = (unsigned short*)(ws + AUG_BYTES);
  float* part = (float*)(ws + 2*AUG_BYTES);

  df_prep<<<(BATCH*NPTS)/4, 256, 0, stream>>>(pts, f1, f2, augI, augJ);
  df_main<<<dim3(JSPLIT, NPTS/ITILE, BATCH), 512, 0, stream>>>(augI, augJ, part);
  df_reduce2<<<BATCH, 1024, 0, stream>>>(part, w, out);
}

// Round 19
// 51.528 us; speedup vs baseline: 1.1536x; 1.1536x over previous
//
#include <hip/hip_runtime.h>

#define BATCH 4
#define NPTS 4096
#define DF 64
#define ITILE 256              // 8 waves x 32 rows
#define JSPLIT 8
#define JCH (NPTS/JSPLIT)      // 512
#define JT 32
#define NT (JCH/JT)            // 16 (even)
#define AUGD 96                // 80 feature (5x K16) + 16 spatial (1x K16)
#define TPB 128                // j-tiles per batch (4096/32)
#define TILEU 3072             // ushorts per packed tile (6 slices x 512)
#define LOG2E 1.4426950408889634f

typedef short short8 __attribute__((ext_vector_type(8)));
typedef float f32x16 __attribute__((ext_vector_type(16)));

__device__ __forceinline__ unsigned short bfb(float x){
  unsigned int u = __float_as_uint(x);
  u += 0x7FFFu + ((u>>16)&1u);          // RNE
  return (unsigned short)(u>>16);
}
__device__ __forceinline__ float bff(unsigned short h){
  return __uint_as_float(((unsigned int)h)<<16);
}
__device__ __forceinline__ float fexp2(float x){   // raw v_exp_f32 (2^x)
  float r; asm("v_exp_f32 %0, %1" : "=v"(r) : "v"(x)); return r;
}

// Packed-tile address (in ushorts) for element col c of j-row jj, batch b.
// Layout [b][T][s][h*32+r][e] (validated absmax 0.0 R15-R18).
__device__ __forceinline__ size_t jaddr(int b, int jj, int c){
  int T = jj>>5, r = jj&31;
  int s = c>>4, h = (c>>3)&1, e = c&7;
  return ((size_t)(b*TPB + T))*TILEU + s*512 + (h*32 + r)*8 + e;
}

// ---------------------------------------------------------------- prepass ---
// R18's parallel prep (validated absmax 0.0): aux columns 64..95 computed by
// all 64 lanes in parallel (lanes 0..31 -> one J-aux column each, lanes
// 32..63 -> one I-aux column each). Same arithmetic order as R15-R17.
__global__ void df_prep(const float* __restrict__ pts,
                        const float* __restrict__ f1,
                        const float* __restrict__ f2,
                        unsigned short* __restrict__ augI,
                        unsigned short* __restrict__ augJ)
{
  int wid = (blockIdx.x<<2) + (threadIdx.x>>6);
  int lane = threadIdx.x & 63;
  if (wid >= BATCH*NPTS) return;
  const int b = wid>>12, jj = wid&4095;
  float v1 = f1[(size_t)wid*DF + lane];
  float v2 = f2[(size_t)wid*DF + lane];
  float r2 = v2*v2;
  #pragma unroll
  for (int s=32;s>=1;s>>=1)
    r2 += __shfl_xor(r2, s);
  augI[(size_t)wid*AUGD + lane] = bfb(2.0f*LOG2E*v1);
  augJ[jaddr(b, jj, lane)] = bfb(v2);

  // broadcast scalars (same-address loads; every lane computes them)
  float px = pts[(size_t)wid*3+0]/0.05f;
  float py = pts[(size_t)wid*3+1]/0.05f;
  float pz = pts[(size_t)wid*3+2]/0.05f;
  float nss = px*px+py*py+pz*pz;

  float fn = LOG2E*r2;
  unsigned short f0_ = bfb(fn); float fr = fn - bff(f0_);
  unsigned short f1_ = bfb(fr); fr -= bff(f1_);
  unsigned short f2_ = bfb(fr);
  float sn = LOG2E*nss;
  unsigned short s0_ = bfb(sn); float sr = sn - bff(s0_);
  unsigned short s1_ = bfb(sr); sr -= bff(s1_);
  unsigned short s2_ = bfb(sr);
  unsigned short hx=bfb(px), hy=bfb(py), hz=bfb(pz);
  unsigned short lxb=bfb(px-bff(hx)), lyb=bfb(py-bff(hy)), lzb=bfb(pz-bff(hz));
  float sx=2.f*LOG2E*px, sy=2.f*LOG2E*py, sz=2.f*LOG2E*pz;
  unsigned short h2x=bfb(sx), h2y=bfb(sy), h2z=bfb(sz);
  unsigned short l2x=bfb(sx-bff(h2x)), l2y=bfb(sy-bff(h2y)), l2z=bfb(sz-bff(h2z));
  unsigned short mone = bfb(-1.0f), one = bfb(1.0f);

  const int k = lane & 31;              // aux column 64+k
  const int idx = (k-16)%3, grp = (k-16)/3;
  unsigned short hj  = idx==0?hx :(idx==1?hy :hz );
  unsigned short lj  = idx==0?lxb:(idx==1?lyb:lzb);
  unsigned short hi2 = idx==0?h2x:(idx==1?h2y:h2z);
  unsigned short li2 = idx==0?l2x:(idx==1?l2y:l2z);

  unsigned short jv, iv;
  if (k<3)       { jv = (k==0)?f0_:(k==1)?f1_:f2_;  iv = mone; }
  else if (k<16) { jv = 0;                           iv = 0;    }
  else if (k<28) { jv = (grp&1)? lj : hj;            iv = (grp>=2)? li2 : hi2; }
  else if (k<31) { jv = (k==28)?s0_:(k==29)?s1_:s2_; iv = mone; }
  else           { jv = one;                         iv = bfb(-sn); }

  if (lane < 32) augJ[jaddr(b, jj, 64+k)] = jv;
  else           augI[(size_t)wid*AUGD + 64 + k] = iv;
}

// ------------------------------------------------------------------- main ---
// R16 VERBATIM (best measured: total 52.1us, absmax 0.0; FETCH 14MB, no
// spill). 512x512 grid x=jc; packed coalesced j-loads; named-reg double
// buffer; independent even/odd accumulator streams; defer-max.

#define LOAD6I(p, v0,v1,v2,v3,v4,v5)                 \
  v0 = *(const short8*)(p);                          \
  v1 = *(const short8*)((p)+16);                     \
  v2 = *(const short8*)((p)+32);                     \
  v3 = *(const short8*)((p)+48);                     \
  v4 = *(const short8*)((p)+64);                     \
  v5 = *(const short8*)((p)+80);

#define LOAD6J(p, v0,v1,v2,v3,v4,v5)                 \
  v0 = *(const short8*)(p);                          \
  v1 = *(const short8*)((p)+512);                    \
  v2 = *(const short8*)((p)+1024);                   \
  v3 = *(const short8*)((p)+1536);                   \
  v4 = *(const short8*)((p)+2048);                   \
  v5 = *(const short8*)((p)+2560);

#define MFMA_BF16 __builtin_amdgcn_mfma_f32_32x32x16_bf16

#define TILE_BODY(v0,v1,v2,v3,v4,v5, M,LP,SA,LQ,SB,SC, PRELOAD)          \
  {                                                                      \
    f32x16 z = {};                                                       \
    f32x16 f0 = MFMA_BF16(v0, bfr0, z, 0,0,0);                           \
    f0 = MFMA_BF16(v1, bfr1, f0,0,0,0);                                  \
    f0 = MFMA_BF16(v2, bfr2, f0,0,0,0);                                  \
    f32x16 f1 = MFMA_BF16(v3, bfr3, z,0,0,0);                            \
    f1 = MFMA_BF16(v4, bfr4, f1,0,0,0);                                  \
    f32x16 accS = MFMA_BF16(v5, bfr5, z,0,0,0);                          \
    PRELOAD                                                              \
    f32x16 accF = f0 + f1;                                               \
    float t0 = fmaxf(accF[0],accF[1]),  t1 = fmaxf(accF[2],accF[3]);     \
    float t2 = fmaxf(accF[4],accF[5]),  t3 = fmaxf(accF[6],accF[7]);     \
    float t4 = fmaxf(accF[8],accF[9]),  t5 = fmaxf(accF[10],accF[11]);   \
    float t6 = fmaxf(accF[12],accF[13]),t7 = fmaxf(accF[14],accF[15]);   \
    t0 = fmaxf(t0,t1); t2 = fmaxf(t2,t3);                                \
    t4 = fmaxf(t4,t5); t6 = fmaxf(t6,t7);                                \
    float tmax = fmaxf(fmaxf(t0,t2), fmaxf(t4,t6));                      \
    if (!__all(tmax <= M)){                                              \
      float mnew = fmaxf(M, tmax);                                       \
      float sg = fexp2(M - mnew);                                        \
      float sg2 = sg*sg;                                                 \
      LQ *= sg; SB *= sg2; SC *= sg; M = mnew;                           \
    }                                                                    \
    _Pragma("unroll")                                                    \
    for (int r=0;r<16;r++){                                              \
      float pv = fexp2(accS[r]);                                         \
      float qv = fexp2(accF[r]-M);                                       \
      LP += pv;                                                          \
      SA = fmaf(pv,pv,SA);                                               \
      LQ += qv;                                                          \
      SB = fmaf(qv,qv,SB);                                               \
      SC = fmaf(pv,qv,SC);                                               \
    }                                                                    \
  }

__global__ __launch_bounds__(512, 2)
void df_main(const unsigned short* __restrict__ augI,
             const unsigned short* __restrict__ augJ,
             float* __restrict__ part)
{
  const int tid = threadIdx.x;
  const int wave = tid>>6, lane = tid&63;
  const int il = lane&31, hk = lane>>5;
  const int jc = blockIdx.x, it = blockIdx.y, b = blockIdx.z;

  const int irow = it*ITILE + wave*32 + il;
  const size_t ibase = ((size_t)(b*NPTS + irow))*AUGD;
  short8 bfr0,bfr1,bfr2,bfr3,bfr4,bfr5;
  LOAD6I(augI + ibase + hk*8, bfr0,bfr1,bfr2,bfr3,bfr4,bfr5)

  const unsigned short* jp =
      augJ + ((size_t)(b*TPB + jc*NT))*TILEU + lane*8;
  const size_t step = TILEU;             // 3072 ushorts per tile

  float lP0=0.f, sA0=0.f, m0=-1e30f, lQ0=0.f, sB0=0.f, sC0=0.f;
  float lP1=0.f, sA1=0.f, m1=-1e30f, lQ1=0.f, sB1=0.f, sC1=0.f;

  short8 xa0,xa1,xa2,xa3,xa4,xa5;        // buffer A (even tiles)
  short8 xb0,xb1,xb2,xb3,xb4,xb5;        // buffer B (odd tiles)
  LOAD6J(jp,        xa0,xa1,xa2,xa3,xa4,xa5)   // t = 0
  LOAD6J(jp + step, xb0,xb1,xb2,xb3,xb4,xb5)   // t = 1
  const unsigned short* jpf = jp + 2*step;     // next to fetch: t = 2

  for (int t=0; t<NT; t+=2){
    TILE_BODY(xa0,xa1,xa2,xa3,xa4,xa5, m0,lP0,sA0,lQ0,sB0,sC0,
      if (t+2 < NT){
        LOAD6J(jpf, xa0,xa1,xa2,xa3,xa4,xa5)   // prefetch t+2 into dead A
        jpf += step;
      })
    TILE_BODY(xb0,xb1,xb2,xb3,xb4,xb5, m1,lP1,sA1,lQ1,sB1,sC1,
      if (t+3 < NT){
        LOAD6J(jpf, xb0,xb1,xb2,xb3,xb4,xb5)   // prefetch t+3 into dead B
        jpf += step;
      })
  }

  // merge stream 1 into stream 0 (disjoint j-subsets; exact rebase)
  float mS = fmaxf(m0, m1);
  float e0 = fexp2(m0-mS), e1 = fexp2(m1-mS);
  float lP = lP0 + lP1;
  float sA = sA0 + sA1;
  float lQ = lQ0*e0 + lQ1*e1;
  float sB = sB0*e0*e0 + sB1*e1*e1;
  float sC = sC0*e0 + sC1*e1;
  float m  = mS;

  // merge the two hk-halves (disjoint j-subsets of same i-row) in-register
  float mo  = __shfl_xor(m, 32);
  float lPo = __shfl_xor(lP,32);
  float sAo = __shfl_xor(sA,32);
  float lQo = __shfl_xor(lQ,32);
  float sBo = __shfl_xor(sB,32);
  float sCo = __shfl_xor(sC,32);
  float mm = fmaxf(m, mo);
  float s0 = fexp2(m-mm), s1 = fexp2(mo-mm);
  lP += lPo; sA += sAo;
  lQ = lQ*s0 + lQo*s1;
  sB = sB*s0*s0 + sBo*s1*s1;
  sC = sC*s0 + sCo*s1;

  if (hk==0){
    const size_t pidx = (((size_t)jc)*((size_t)BATCH*NPTS)
                         + (size_t)b*NPTS + irow)*8;
    float4 v0 = {lP, sA, mm, lQ};
    float4 v1 = {sB, sC, 0.f, 0.f};
    *(float4*)(part + pidx)     = v0;    // full 32B/row -> no partial lines
    *(float4*)(part + pidx + 4) = v1;
  }
}

// ----------------------------------------------------------------- reduce ---
// R16's proven pair: 64-block reduce (adequate parallelism — the R18 4-block
// fusion starved CUs and cost +7us) + tiny final.
template<int SETS>
__global__ void df_reduce(const float* __restrict__ part,
                          const float* __restrict__ w,
                          float* __restrict__ ws2)
{
  const int jb = blockIdx.x, b = blockIdx.y;
  const int tid = threadIdx.x;
  const int i = jb*256 + tid;
  const size_t stride = (size_t)BATCH*NPTS*8;
  const size_t base = ((size_t)b*NPTS + i)*8;
  float mx = -1e30f;
  #pragma unroll
  for (int k=0;k<SETS;k++)
    mx = fmaxf(mx, part[base + (size_t)k*stride + 2]);
  float lP=0,sA=0,lQ=0,sB=0,sC=0;
  #pragma unroll
  for (int k=0;k<SETS;k++){
    const float* pp = part + base + (size_t)k*stride;
    lP += pp[0]; sA += pp[1];
    float sg = fexp2(pp[2]-mx);
    lQ += sg*pp[3]; sB += sg*sg*pp[4]; sC += sg*pp[5];
  }
  float res = sA/(lP*lP) + sB/(lQ*lQ) - 2.0f*sC/(lP*lQ);
  float acc = w[(size_t)b*NPTS + i]*res;
  __shared__ float red[256];
  red[tid]=acc; __syncthreads();
  for (int s=128;s>0;s>>=1){
    if (tid<s) red[tid]+=red[tid+s];
    __syncthreads();
  }
  if (tid==0) ws2[b*16+jb]=red[0];
}

__global__ void df_final(const float* __restrict__ ws2, float* __restrict__ out){
  int b = threadIdx.x;
  if (b < BATCH){
    float s=0.f;
    #pragma unroll
    for (int k=0;k<16;k++) s += ws2[b*16+k];
    out[b]=s;
  }
}

// ----------------------------------------------------------------- launch ---
extern "C" void kernel_launch(void* const* d_in, const int* in_sizes, int n_in,
                              void* d_out, int out_size, void* d_ws, size_t ws_size,
                              hipStream_t stream) {
  const float* pts = (const float*)d_in[0];
  const float* w   = (const float*)d_in[1];
  const float* f1  = (const float*)d_in[2];
  const float* f2  = (const float*)d_in[3];
  float* out = (float*)d_out;

  unsigned char* ws = (unsigned char*)d_ws;
  const size_t AUG_BYTES = (size_t)BATCH*NPTS*AUGD*2;        // 3,145,728 each
  unsigned short* augI = (unsigned short*)(ws);
  unsigned short* augJ = (unsigned short*)(ws + AUG_BYTES);
  float* part = (float*)(ws + 2*AUG_BYTES);

  const size_t PART8 = (size_t)JSPLIT*BATCH*NPTS*8*4;        // 4,194,304
  float* ws2 = (float*)(ws + 2*AUG_BYTES + PART8);

  df_prep<<<(BATCH*NPTS)/4, 256, 0, stream>>>(pts, f1, f2, augI, augJ);
  df_main<<<dim3(JSPLIT, NPTS/ITILE, BATCH), 512, 0, stream>>>(augI, augJ, part);
  df_reduce<JSPLIT><<<dim3(16, BATCH), 256, 0, stream>>>(part, w, ws2);
  df_final<<<1, 64, 0, stream>>>(ws2, out);
}